// Round 13
// baseline (365.512 us; speedup 1.0000x reference)
//
#include <hip/hip_runtime.h>
#include <cstdint>
#include <math.h>

#define TT 2048
#define CC 1024
#define HH 16
#define DH 64
#define BB 4
#define MM 8192   // B*T

typedef unsigned short u16;
typedef __bf16 bf16_t;
typedef bf16_t bf16x8 __attribute__((ext_vector_type(8)));
typedef float f32x4 __attribute__((ext_vector_type(4)));

// fp32 -> bf16 round-to-nearest-even (scalar)
static __device__ inline u16 f2bf(float f) {
    unsigned int u = __builtin_bit_cast(unsigned int, f);
    unsigned int lsb = (u >> 16) & 1u;
    u += 0x7fffu + lsb;
    return (u16)(u >> 16);
}

// packed 2xfp32 -> 2xbf16 (gfx950 v_cvt_pk_bf16_f32, RNE)
static __device__ inline unsigned int cvt_pk_bf16(float a, float b) {
    unsigned int r;
    asm volatile("v_cvt_pk_bf16_f32 %0, %1, %2" : "=v"(r) : "v"(a), "v"(b));
    return r;
}

// async 16B global->LDS (LDS dest wave-uniform + lane*16B)
#define GLL16(gptr, lptr)                                                            \
    __builtin_amdgcn_global_load_lds(                                                \
        (__attribute__((address_space(1))) void*)(gptr),                             \
        (__attribute__((address_space(3))) void*)(lptr), 16, 0, 0)

// ---------------- fused prep kernel (r18-verified) ----------------
__global__ void __launch_bounds__(256)
prep_kernel(const float* __restrict__ x, u16* __restrict__ xb,
            const float* __restrict__ Wq, u16* __restrict__ wqt,
            const float* __restrict__ Wo, u16* __restrict__ wot) {
    const int bid = blockIdx.x;
    if (bid < 8192) {                       // cast x
        int i = bid * 256 + threadIdx.x;
        float4 v = ((const float4*)x)[i];
        uint2 o;
        o.x = cvt_pk_bf16(v.x, v.y);
        o.y = cvt_pk_bf16(v.z, v.w);
        ((uint2*)xb)[i] = o;
        return;
    }
    __shared__ u16 tile[32 * 34];
    const float* W; u16* Wt; int N, n0, k0;
    if (bid < 8192 + 3072) {                // W_qkv
        int idx = bid - 8192;
        W = Wq; Wt = wqt; N = 3 * CC;
        n0 = (idx % 96) * 32; k0 = (idx / 96) * 32;
    } else {                                // W_out
        int idx = bid - 11264;
        W = Wo; Wt = wot; N = CC;
        n0 = (idx % 32) * 32; k0 = (idx / 32) * 32;
    }
    const int tx = threadIdx.x & 31;
    const int ty = threadIdx.x >> 5;
#pragma unroll
    for (int i = 0; i < 4; ++i) {
        int k = ty + i * 8;
        tile[tx * 34 + k] = f2bf(W[(size_t)(k0 + k) * N + n0 + tx]);
    }
    __syncthreads();
    const int tx2 = threadIdx.x & 15;
    const int ty2 = threadIdx.x >> 4;
#pragma unroll
    for (int i = 0; i < 2; ++i) {
        int r = ty2 + i * 16;
        *(unsigned int*)&Wt[(size_t)(n0 + r) * CC + k0 + 2 * tx2] =
            *(unsigned int*)&tile[r * 34 + 2 * tx2];
    }
}

// ---------------- GEMM: C[M,N] = A[M,K] @ Bt[N,K]^T + bias ----------------
// ROUND-20/21: r10-verified 2-phase 128x128 + XCD-chunked blockIdx swizzle
// (T1). Mechanism: default round-robin makes all 8 XCDs stream the whole A
// matrix (FETCH 71.7MB vs ~22MB ideal); chunking gives each XCD a contiguous
// run of nwg/8 tiles (8 full m-rows for gemm1, A-panels ~2MB/XCD -> L2-fits)
// so A-panels are fetched once per XCD. In this 2-phase kernel the per-K-step
// vmcnt(0)-drain duration = slowest load, so converting HBM-miss (~900cy)
// drains to L2-hit (~200cy) drains attacks the stall directly. Bijective:
// both grids (1536, 512) are %8==0. (r12 audit: bid = linear dispatch index,
// bid&7 = XCD under round-robin; perf-only assumption.)
// + r16 LDS XOR swizzle (bank-conflicts 0, verified).
// MODE 0: A is y in [B,H,T,Dh] bf16; write fp32 C.
// MODE 1: A row-major [M,K] bf16; qkv scatter epilogue (V^T key-permuted).
template <int MODE>
__global__ void __launch_bounds__(256)
gemm_bt_kernel(const u16* __restrict__ A, const u16* __restrict__ Bt,
               const float* __restrict__ bias, float* __restrict__ Cout,
               u16* __restrict__ qws, u16* __restrict__ kws, u16* __restrict__ vtws,
               int Mdim, int Ndim, int Kdim) {
    __shared__ u16 As[2][128 * 32];
    __shared__ u16 Bs[2][128 * 32];

    const int tid  = threadIdx.x;
    const int w    = tid >> 6;
    const int lane = tid & 63;
    const int l15  = lane & 15;
    const int quad = lane >> 4;
    const int wm   = (w & 1) * 64;
    const int wn   = (w >> 1) * 64;

    // XCD-chunked swizzle: XCD j (= bid%8 by round-robin dispatch) processes
    // the contiguous tile range [j*nwg/8, (j+1)*nwg/8).
    const int nwg = gridDim.x * gridDim.y;
    const int bid = blockIdx.y * gridDim.x + blockIdx.x;
    const int swz = (bid & 7) * (nwg >> 3) + (bid >> 3);
    const int m0  = (swz / gridDim.x) * 128;
    const int n0  = (swz % gridDim.x) * 128;

    const int row0  = tid >> 2;
    const int row1  = row0 + 64;
    const int colsw = (((tid & 3) ^ ((row0 >> 1) & 3))) << 3;

    f32x4 acc[4][4];
#pragma unroll
    for (int i = 0; i < 4; ++i)
#pragma unroll
        for (int j = 0; j < 4; ++j) acc[i][j] = (f32x4){0.f, 0.f, 0.f, 0.f};

    auto stageA = [&](int buf, int kc) {
        if (MODE == 0) {
            int kcc = kc + colsw, h = kcc >> 6, d = kcc & 63;
            int m = m0 + row0, b = m >> 11, t = m & 2047;
            GLL16(&A[(((size_t)(b * HH + h) * TT + t) * DH) + d], &As[buf][tid * 8]);
            m = m0 + row1; b = m >> 11; t = m & 2047;
            GLL16(&A[(((size_t)(b * HH + h) * TT + t) * DH) + d], &As[buf][(tid + 256) * 8]);
        } else {
            GLL16(&A[(size_t)(m0 + row0) * Kdim + kc + colsw], &As[buf][tid * 8]);
            GLL16(&A[(size_t)(m0 + row1) * Kdim + kc + colsw], &As[buf][(tid + 256) * 8]);
        }
    };

    stageA(0, 0);
    GLL16(&Bt[(size_t)(n0 + row0) * Kdim + colsw], &Bs[0][tid * 8]);
    GLL16(&Bt[(size_t)(n0 + row1) * Kdim + colsw], &Bs[0][(tid + 256) * 8]);

    const int csw = (quad ^ ((l15 >> 1) & 3)) * 8;

    const int nsteps = Kdim >> 5;
    for (int it = 0; it < nsteps; ++it) {
        const int buf = it & 1;
        __syncthreads();

        if (it + 1 < nsteps) {
            const int nbuf = buf ^ 1;
            const int kc = (it + 1) << 5;
            stageA(nbuf, kc);
            GLL16(&Bt[(size_t)(n0 + row0) * Kdim + kc + colsw], &Bs[nbuf][tid * 8]);
            GLL16(&Bt[(size_t)(n0 + row1) * Kdim + kc + colsw], &Bs[nbuf][(tid + 256) * 8]);
        }

        bf16x8 af[4], bfm[4];
#pragma unroll
        for (int mt = 0; mt < 4; ++mt)
            af[mt] = *(const bf16x8*)&As[buf][(wm + mt * 16 + l15) * 32 + csw];
#pragma unroll
        for (int nt = 0; nt < 4; ++nt)
            bfm[nt] = *(const bf16x8*)&Bs[buf][(wn + nt * 16 + l15) * 32 + csw];
#pragma unroll
        for (int mt = 0; mt < 4; ++mt)
#pragma unroll
            for (int nt = 0; nt < 4; ++nt)
                acc[mt][nt] = __builtin_amdgcn_mfma_f32_16x16x32_bf16(
                    af[mt], bfm[nt], acc[mt][nt], 0, 0, 0);
    }

#pragma unroll
    for (int mt = 0; mt < 4; ++mt) {
        int mrow_base = m0 + wm + mt * 16 + quad * 4;
#pragma unroll
        for (int nt = 0; nt < 4; ++nt) {
            int ncol = n0 + wn + nt * 16 + l15;
            float bv = bias[ncol];
            if (MODE == 0) {
#pragma unroll
                for (int r = 0; r < 4; ++r)
                    Cout[(size_t)(mrow_base + r) * Ndim + ncol] = acc[mt][nt][r] + bv;
            } else {
                int which = ncol >> 10, c = ncol & 1023;
                int h = c >> 6, d = c & 63;
                if (which == 2) {
                    int b = mrow_base >> 11, t = mrow_base & 2047;
                    int bh = b * HH + h;
                    int ch = (t >> 2) & 15;
                    int chp = (ch & 8) | (((ch >> 1) & 1) << 2) | ((ch & 1) << 1) | ((ch >> 2) & 1);
                    int tp = (t & ~63) | (chp << 2);
                    uint2 pv;
                    pv.x = cvt_pk_bf16(acc[mt][nt][0] + bv, acc[mt][nt][1] + bv);
                    pv.y = cvt_pk_bf16(acc[mt][nt][2] + bv, acc[mt][nt][3] + bv);
                    *(uint2*)&vtws[((size_t)bh * DH + d) * TT + tp] = pv;
                } else {
#pragma unroll
                    for (int r = 0; r < 4; ++r) {
                        int mrow = mrow_base + r;
                        int b = mrow >> 11, t = mrow & 2047;
                        int bh = b * HH + h;
                        float val = acc[mt][nt][r] + bv;
                        if (which == 0) {
                            qws[((size_t)bh * TT + t) * DH + d] = f2bf(val * 0.18033688f);
                        } else {
                            kws[((size_t)bh * TT + t) * DH + d] = f2bf(val);
                        }
                    }
                }
            }
        }
    }
}

// ---------------- flash attention v12: zero-LDS P path, 4 blocks/CU ----------------
// ROUND-20/21: __launch_bounds__(256,3) -> (256,4). The kernel compiles to 84
// VGPR (measured r7-r10), comfortably under the 128 cap at 4 waves/SIMD —
// unlike r6's ~150-VGPR datapath that spilled under the same bound. LDS
// 34816B x 4 = 139KB <= 160KB -> 4 blocks/CU, 16 waves/CU (+33% latency
// hiding). Grid 1024 = exactly 4 blocks/CU. Watch WRITE_SIZE for any spill
// signature (must stay 16MB).
__global__ void __launch_bounds__(256, 4)
attn_kernel(const u16* __restrict__ qws, const u16* __restrict__ kws,
            const u16* __restrict__ vtws, u16* __restrict__ yws) {
    __shared__ u16 Ks[2][64 * 68];
    __shared__ u16 Vs[2][64 * 68];

    const int tid  = threadIdx.x;
    const int w    = tid >> 6;
    const int lane = tid & 63;
    const int l15  = lane & 15;
    const int quad = lane >> 4;
    const int bh   = blockIdx.x;
    const int qt   = 15 - blockIdx.y;

    const u16* Kbase = kws + (size_t)bh * TT * DH;
    const u16* Vbase = vtws + (size_t)bh * DH * TT;

    const int srow  = tid >> 2;
    const int sc16  = (tid & 3) << 4;

    bf16x8 aones;
#pragma unroll
    for (int i = 0; i < 8; ++i) aones[i] = __builtin_bit_cast(bf16_t, (u16)0x3F80);

    const int q0     = qt * 128;
    const int qr0    = q0 + w * 32;
    const int ntiles = (q0 + 128) >> 6;

    const u16* Qp = qws + ((size_t)bh * TT + qr0) * DH;
    bf16x8 bqa[2], bqb[2];
#pragma unroll
    for (int kk = 0; kk < 2; ++kk) {
        bqa[kk] = *(const bf16x8*)&Qp[l15 * DH + kk * 32 + quad * 8];
        bqb[kk] = *(const bf16x8*)&Qp[(16 + l15) * DH + kk * 32 + quad * 8];
    }

    f32x4 o[2][4], ol[2];
#pragma unroll
    for (int qg = 0; qg < 2; ++qg) {
#pragma unroll
        for (int dt = 0; dt < 4; ++dt) o[qg][dt] = (f32x4){0.f, 0.f, 0.f, 0.f};
        ol[qg] = (f32x4){0.f, 0.f, 0.f, 0.f};
    }

    uint4 pk0 = *(const uint4*)&Kbase[(size_t)srow * DH + sc16];
    uint4 pk1 = *(const uint4*)&Kbase[(size_t)srow * DH + sc16 + 8];
    uint4 pv0 = *(const uint4*)&Vbase[(size_t)srow * TT + sc16];
    uint4 pv1 = *(const uint4*)&Vbase[(size_t)srow * TT + sc16 + 8];
    *(uint4*)&Ks[0][srow * 68 + sc16]     = pk0;
    *(uint4*)&Ks[0][srow * 68 + sc16 + 8] = pk1;
    *(uint4*)&Vs[0][srow * 68 + sc16]     = pv0;
    *(uint4*)&Vs[0][srow * 68 + sc16 + 8] = pv1;
    if (ntiles > 1) {
        pk0 = *(const uint4*)&Kbase[(size_t)(64 + srow) * DH + sc16];
        pk1 = *(const uint4*)&Kbase[(size_t)(64 + srow) * DH + sc16 + 8];
        pv0 = *(const uint4*)&Vbase[(size_t)srow * TT + 64 + sc16];
        pv1 = *(const uint4*)&Vbase[(size_t)srow * TT + 64 + sc16 + 8];
    }

    for (int it = 0; it < ntiles; ++it) {
        const int buf = it & 1;
        __syncthreads();

        if (it + 1 < ntiles) {
            *(uint4*)&Ks[buf ^ 1][srow * 68 + sc16]     = pk0;
            *(uint4*)&Ks[buf ^ 1][srow * 68 + sc16 + 8] = pk1;
            *(uint4*)&Vs[buf ^ 1][srow * 68 + sc16]     = pv0;
            *(uint4*)&Vs[buf ^ 1][srow * 68 + sc16 + 8] = pv1;
            if (it + 2 < ntiles) {
                int jn = (it + 2) << 6;
                pk0 = *(const uint4*)&Kbase[(size_t)(jn + srow) * DH + sc16];
                pk1 = *(const uint4*)&Kbase[(size_t)(jn + srow) * DH + sc16 + 8];
                pv0 = *(const uint4*)&Vbase[(size_t)srow * TT + jn + sc16];
                pv1 = *(const uint4*)&Vbase[(size_t)srow * TT + jn + sc16 + 8];
            }
        }

        const int j0 = it << 6;
        if (j0 > qr0 + 31) continue;

        bf16x8 ak[8];
#pragma unroll
        for (int kk = 0; kk < 2; ++kk)
#pragma unroll
            for (int kt = 0; kt < 4; ++kt)
                ak[kk * 4 + kt] =
                    *(const bf16x8*)&Ks[buf][(kt * 16 + l15) * 68 + kk * 32 + quad * 8];

        bf16x8 avr[8];
#pragma unroll
        for (int kk = 0; kk < 2; ++kk)
#pragma unroll
            for (int dt = 0; dt < 4; ++dt)
                avr[kk * 4 + dt] =
                    *(const bf16x8*)&Vs[buf][(dt * 16 + l15) * 68 + kk * 32 + quad * 8];

        f32x4 sa[4], sb[4];
#pragma unroll
        for (int kt = 0; kt < 4; ++kt) {
            sa[kt] = (f32x4){0.f, 0.f, 0.f, 0.f};
            sb[kt] = (f32x4){0.f, 0.f, 0.f, 0.f};
        }
#pragma unroll
        for (int kk = 0; kk < 2; ++kk)
#pragma unroll
            for (int kt = 0; kt < 4; ++kt)
                sa[kt] = __builtin_amdgcn_mfma_f32_16x16x32_bf16(ak[kk * 4 + kt], bqa[kk], sa[kt], 0, 0, 0);
#pragma unroll
        for (int kk = 0; kk < 2; ++kk)
#pragma unroll
            for (int kt = 0; kt < 4; ++kt)
                sb[kt] = __builtin_amdgcn_mfma_f32_16x16x32_bf16(ak[kk * 4 + kt], bqb[kk], sb[kt], 0, 0, 0);

        if (j0 + 63 > qr0) {
            int qy0 = qr0 + l15;
            int qy1 = qr0 + 16 + l15;
#pragma unroll
            for (int kt = 0; kt < 4; ++kt)
#pragma unroll
                for (int r = 0; r < 4; ++r) {
                    int key = j0 + kt * 16 + quad * 4 + r;
                    if (key > qy0) sa[kt][r] = -INFINITY;
                    if (key > qy1) sb[kt][r] = -INFINITY;
                }
        }

#pragma unroll
        for (int kt = 0; kt < 4; ++kt)
#pragma unroll
            for (int r = 0; r < 4; ++r) {
                sa[kt][r] = __builtin_amdgcn_exp2f(sa[kt][r]);
                sb[kt][r] = __builtin_amdgcn_exp2f(sb[kt][r]);
            }

        uint4 ua0, ua1, ub0, ub1;
        ua0.x = cvt_pk_bf16(sa[0][0], sa[0][1]);
        ua0.y = cvt_pk_bf16(sa[0][2], sa[0][3]);
        ua0.z = cvt_pk_bf16(sa[1][0], sa[1][1]);
        ua0.w = cvt_pk_bf16(sa[1][2], sa[1][3]);
        ua1.x = cvt_pk_bf16(sa[2][0], sa[2][1]);
        ua1.y = cvt_pk_bf16(sa[2][2], sa[2][3]);
        ua1.z = cvt_pk_bf16(sa[3][0], sa[3][1]);
        ua1.w = cvt_pk_bf16(sa[3][2], sa[3][3]);
        ub0.x = cvt_pk_bf16(sb[0][0], sb[0][1]);
        ub0.y = cvt_pk_bf16(sb[0][2], sb[0][3]);
        ub0.z = cvt_pk_bf16(sb[1][0], sb[1][1]);
        ub0.w = cvt_pk_bf16(sb[1][2], sb[1][3]);
        ub1.x = cvt_pk_bf16(sb[2][0], sb[2][1]);
        ub1.y = cvt_pk_bf16(sb[2][2], sb[2][3]);
        ub1.z = cvt_pk_bf16(sb[3][0], sb[3][1]);
        ub1.w = cvt_pk_bf16(sb[3][2], sb[3][3]);
        bf16x8 bpa0 = __builtin_bit_cast(bf16x8, ua0);
        bf16x8 bpa1 = __builtin_bit_cast(bf16x8, ua1);
        bf16x8 bpb0 = __builtin_bit_cast(bf16x8, ub0);
        bf16x8 bpb1 = __builtin_bit_cast(bf16x8, ub1);

#pragma unroll
        for (int dt = 0; dt < 4; ++dt)
            o[0][dt] = __builtin_amdgcn_mfma_f32_16x16x32_bf16(avr[dt], bpa0, o[0][dt], 0, 0, 0);
        ol[0] = __builtin_amdgcn_mfma_f32_16x16x32_bf16(aones, bpa0, ol[0], 0, 0, 0);
#pragma unroll
        for (int dt = 0; dt < 4; ++dt)
            o[0][dt] = __builtin_amdgcn_mfma_f32_16x16x32_bf16(avr[4 + dt], bpa1, o[0][dt], 0, 0, 0);
        ol[0] = __builtin_amdgcn_mfma_f32_16x16x32_bf16(aones, bpa1, ol[0], 0, 0, 0);
#pragma unroll
        for (int dt = 0; dt < 4; ++dt)
            o[1][dt] = __builtin_amdgcn_mfma_f32_16x16x32_bf16(avr[dt], bpb0, o[1][dt], 0, 0, 0);
        ol[1] = __builtin_amdgcn_mfma_f32_16x16x32_bf16(aones, bpb0, ol[1], 0, 0, 0);
#pragma unroll
        for (int dt = 0; dt < 4; ++dt)
            o[1][dt] = __builtin_amdgcn_mfma_f32_16x16x32_bf16(avr[4 + dt], bpb1, o[1][dt], 0, 0, 0);
        ol[1] = __builtin_amdgcn_mfma_f32_16x16x32_bf16(aones, bpb1, ol[1], 0, 0, 0);
    }

#pragma unroll
    for (int qg = 0; qg < 2; ++qg) {
        float rinv = __builtin_amdgcn_rcpf(ol[qg][0]);
        int t = qr0 + qg * 16 + l15;
#pragma unroll
        for (int dt = 0; dt < 4; ++dt) {
            uint2 yv;
            yv.x = cvt_pk_bf16(o[qg][dt][0] * rinv, o[qg][dt][1] * rinv);
            yv.y = cvt_pk_bf16(o[qg][dt][2] * rinv, o[qg][dt][3] * rinv);
            *(uint2*)&yws[((size_t)bh * TT + t) * DH + dt * 16 + quad * 4] = yv;
        }
    }
}

// ---------------- launch ----------------

extern "C" void kernel_launch(void* const* d_in, const int* in_sizes, int n_in,
                              void* d_out, int out_size, void* d_ws, size_t ws_size,
                              hipStream_t stream) {
    const float* x     = (const float*)d_in[0];
    const float* W_qkv = (const float*)d_in[1];
    const float* b_qkv = (const float*)d_in[2];
    const float* W_out = (const float*)d_in[3];
    const float* b_out = (const float*)d_in[4];
    float* out = (float*)d_out;

    char* ws = (char*)d_ws;
    u16* xb   = (u16*)ws; ws += (size_t)MM * CC * 2;       // x bf16        16 MB
    u16* wqt  = (u16*)ws; ws += (size_t)3 * CC * CC * 2;   // W_qkv^T bf16   6 MB
    u16* wot  = (u16*)ws; ws += (size_t)CC * CC * 2;       // W_out^T bf16   2 MB
    u16* qws  = (u16*)ws; ws += (size_t)MM * CC * 2;       // Q [B,H,T,Dh]  16 MB
    u16* kws  = (u16*)ws; ws += (size_t)MM * CC * 2;       // K [B,H,T,Dh]  16 MB
    u16* vtws = (u16*)ws; ws += (size_t)MM * CC * 2;       // V^T (key-permuted) 16 MB
    u16* yws  = (u16*)ws; ws += (size_t)MM * CC * 2;       // y [B,H,T,Dh]  16 MB

    prep_kernel<<<8192 + 3072 + 1024, 256, 0, stream>>>(x, xb, W_qkv, wqt, W_out, wot);

    gemm_bt_kernel<1><<<dim3(24, 64), 256, 0, stream>>>(
        xb, wqt, b_qkv, nullptr, qws, kws, vtws, MM, 3 * CC, CC);

    attn_kernel<<<dim3(BB * HH, 16), 256, 0, stream>>>(qws, kws, vtws, yws);

    gemm_bt_kernel<0><<<dim3(8, 64), 256, 0, stream>>>(
        yws, wot, b_out, out, nullptr, nullptr, nullptr, MM, CC, CC);
}

// Round 14
// 234.410 us; speedup vs baseline: 1.5593x; 1.5593x over previous
//
#include <hip/hip_runtime.h>
#include <cstdint>
#include <math.h>

#define TT 2048
#define CC 1024
#define HH 16
#define DH 64
#define BB 4
#define MM 8192   // B*T

typedef unsigned short u16;
typedef __bf16 bf16_t;
typedef bf16_t bf16x8 __attribute__((ext_vector_type(8)));
typedef float f32x4 __attribute__((ext_vector_type(4)));

// fp32 -> bf16 round-to-nearest-even (scalar)
static __device__ inline u16 f2bf(float f) {
    unsigned int u = __builtin_bit_cast(unsigned int, f);
    unsigned int lsb = (u >> 16) & 1u;
    u += 0x7fffu + lsb;
    return (u16)(u >> 16);
}

// packed 2xfp32 -> 2xbf16 (gfx950 v_cvt_pk_bf16_f32, RNE)
static __device__ inline unsigned int cvt_pk_bf16(float a, float b) {
    unsigned int r;
    asm volatile("v_cvt_pk_bf16_f32 %0, %1, %2" : "=v"(r) : "v"(a), "v"(b));
    return r;
}

// async 16B global->LDS (LDS dest wave-uniform + lane*16B)
#define GLL16(gptr, lptr)                                                            \
    __builtin_amdgcn_global_load_lds(                                                \
        (__attribute__((address_space(1))) void*)(gptr),                             \
        (__attribute__((address_space(3))) void*)(lptr), 16, 0, 0)

// ---------------- fused prep kernel (r18-verified) ----------------
__global__ void __launch_bounds__(256)
prep_kernel(const float* __restrict__ x, u16* __restrict__ xb,
            const float* __restrict__ Wq, u16* __restrict__ wqt,
            const float* __restrict__ Wo, u16* __restrict__ wot) {
    const int bid = blockIdx.x;
    if (bid < 8192) {                       // cast x
        int i = bid * 256 + threadIdx.x;
        float4 v = ((const float4*)x)[i];
        uint2 o;
        o.x = cvt_pk_bf16(v.x, v.y);
        o.y = cvt_pk_bf16(v.z, v.w);
        ((uint2*)xb)[i] = o;
        return;
    }
    __shared__ u16 tile[32 * 34];
    const float* W; u16* Wt; int N, n0, k0;
    if (bid < 8192 + 3072) {                // W_qkv
        int idx = bid - 8192;
        W = Wq; Wt = wqt; N = 3 * CC;
        n0 = (idx % 96) * 32; k0 = (idx / 96) * 32;
    } else {                                // W_out
        int idx = bid - 11264;
        W = Wo; Wt = wot; N = CC;
        n0 = (idx % 32) * 32; k0 = (idx / 32) * 32;
    }
    const int tx = threadIdx.x & 31;
    const int ty = threadIdx.x >> 5;
#pragma unroll
    for (int i = 0; i < 4; ++i) {
        int k = ty + i * 8;
        tile[tx * 34 + k] = f2bf(W[(size_t)(k0 + k) * N + n0 + tx]);
    }
    __syncthreads();
    const int tx2 = threadIdx.x & 15;
    const int ty2 = threadIdx.x >> 4;
#pragma unroll
    for (int i = 0; i < 2; ++i) {
        int r = ty2 + i * 16;
        *(unsigned int*)&Wt[(size_t)(n0 + r) * CC + k0 + 2 * tx2] =
            *(unsigned int*)&tile[r * 34 + 2 * tx2];
    }
}

// ---------------- GEMM: C[M,N] = A[M,K] @ Bt[N,K]^T + bias ----------------
// r10-verified 2-phase 128x128 + XCD-chunked blockIdx swizzle (T1, r20).
// Mechanism: default round-robin makes all 8 XCDs stream the whole A matrix
// (FETCH 71.7MB vs ~22MB ideal); chunking gives each XCD a contiguous run of
// nwg/8 tiles (8 full m-rows for gemm1, A-panels ~2MB/XCD -> L2-fits) so
// A-panels are fetched once per XCD. In this 2-phase kernel the per-K-step
// vmcnt(0)-drain duration = slowest load, so converting HBM-miss (~900cy)
// drains to L2-hit (~200cy) drains attacks the stall directly. Bijective:
// both grids (1536, 512) are %8==0.
// + r16 LDS XOR swizzle (bank-conflicts 0, verified).
// MODE 0: A is y in [B,H,T,Dh] bf16; write fp32 C.
// MODE 1: A row-major [M,K] bf16; qkv scatter epilogue (V^T key-permuted).
template <int MODE>
__global__ void __launch_bounds__(256)
gemm_bt_kernel(const u16* __restrict__ A, const u16* __restrict__ Bt,
               const float* __restrict__ bias, float* __restrict__ Cout,
               u16* __restrict__ qws, u16* __restrict__ kws, u16* __restrict__ vtws,
               int Mdim, int Ndim, int Kdim) {
    __shared__ u16 As[2][128 * 32];
    __shared__ u16 Bs[2][128 * 32];

    const int tid  = threadIdx.x;
    const int w    = tid >> 6;
    const int lane = tid & 63;
    const int l15  = lane & 15;
    const int quad = lane >> 4;
    const int wm   = (w & 1) * 64;
    const int wn   = (w >> 1) * 64;

    // XCD-chunked swizzle: XCD j (= bid%8 by round-robin dispatch) processes
    // the contiguous tile range [j*nwg/8, (j+1)*nwg/8).
    const int nwg = gridDim.x * gridDim.y;
    const int bid = blockIdx.y * gridDim.x + blockIdx.x;
    const int swz = (bid & 7) * (nwg >> 3) + (bid >> 3);
    const int m0  = (swz / gridDim.x) * 128;
    const int n0  = (swz % gridDim.x) * 128;

    const int row0  = tid >> 2;
    const int row1  = row0 + 64;
    const int colsw = (((tid & 3) ^ ((row0 >> 1) & 3))) << 3;

    f32x4 acc[4][4];
#pragma unroll
    for (int i = 0; i < 4; ++i)
#pragma unroll
        for (int j = 0; j < 4; ++j) acc[i][j] = (f32x4){0.f, 0.f, 0.f, 0.f};

    auto stageA = [&](int buf, int kc) {
        if (MODE == 0) {
            int kcc = kc + colsw, h = kcc >> 6, d = kcc & 63;
            int m = m0 + row0, b = m >> 11, t = m & 2047;
            GLL16(&A[(((size_t)(b * HH + h) * TT + t) * DH) + d], &As[buf][tid * 8]);
            m = m0 + row1; b = m >> 11; t = m & 2047;
            GLL16(&A[(((size_t)(b * HH + h) * TT + t) * DH) + d], &As[buf][(tid + 256) * 8]);
        } else {
            GLL16(&A[(size_t)(m0 + row0) * Kdim + kc + colsw], &As[buf][tid * 8]);
            GLL16(&A[(size_t)(m0 + row1) * Kdim + kc + colsw], &As[buf][(tid + 256) * 8]);
        }
    };

    stageA(0, 0);
    GLL16(&Bt[(size_t)(n0 + row0) * Kdim + colsw], &Bs[0][tid * 8]);
    GLL16(&Bt[(size_t)(n0 + row1) * Kdim + colsw], &Bs[0][(tid + 256) * 8]);

    const int csw = (quad ^ ((l15 >> 1) & 3)) * 8;

    const int nsteps = Kdim >> 5;
    for (int it = 0; it < nsteps; ++it) {
        const int buf = it & 1;
        __syncthreads();

        if (it + 1 < nsteps) {
            const int nbuf = buf ^ 1;
            const int kc = (it + 1) << 5;
            stageA(nbuf, kc);
            GLL16(&Bt[(size_t)(n0 + row0) * Kdim + kc + colsw], &Bs[nbuf][tid * 8]);
            GLL16(&Bt[(size_t)(n0 + row1) * Kdim + kc + colsw], &Bs[nbuf][(tid + 256) * 8]);
        }

        bf16x8 af[4], bfm[4];
#pragma unroll
        for (int mt = 0; mt < 4; ++mt)
            af[mt] = *(const bf16x8*)&As[buf][(wm + mt * 16 + l15) * 32 + csw];
#pragma unroll
        for (int nt = 0; nt < 4; ++nt)
            bfm[nt] = *(const bf16x8*)&Bs[buf][(wn + nt * 16 + l15) * 32 + csw];
#pragma unroll
        for (int mt = 0; mt < 4; ++mt)
#pragma unroll
            for (int nt = 0; nt < 4; ++nt)
                acc[mt][nt] = __builtin_amdgcn_mfma_f32_16x16x32_bf16(
                    af[mt], bfm[nt], acc[mt][nt], 0, 0, 0);
    }

#pragma unroll
    for (int mt = 0; mt < 4; ++mt) {
        int mrow_base = m0 + wm + mt * 16 + quad * 4;
#pragma unroll
        for (int nt = 0; nt < 4; ++nt) {
            int ncol = n0 + wn + nt * 16 + l15;
            float bv = bias[ncol];
            if (MODE == 0) {
#pragma unroll
                for (int r = 0; r < 4; ++r)
                    Cout[(size_t)(mrow_base + r) * Ndim + ncol] = acc[mt][nt][r] + bv;
            } else {
                int which = ncol >> 10, c = ncol & 1023;
                int h = c >> 6, d = c & 63;
                if (which == 2) {
                    int b = mrow_base >> 11, t = mrow_base & 2047;
                    int bh = b * HH + h;
                    int ch = (t >> 2) & 15;
                    int chp = (ch & 8) | (((ch >> 1) & 1) << 2) | ((ch & 1) << 1) | ((ch >> 2) & 1);
                    int tp = (t & ~63) | (chp << 2);
                    uint2 pv;
                    pv.x = cvt_pk_bf16(acc[mt][nt][0] + bv, acc[mt][nt][1] + bv);
                    pv.y = cvt_pk_bf16(acc[mt][nt][2] + bv, acc[mt][nt][3] + bv);
                    *(uint2*)&vtws[((size_t)bh * DH + d) * TT + tp] = pv;
                } else {
#pragma unroll
                    for (int r = 0; r < 4; ++r) {
                        int mrow = mrow_base + r;
                        int b = mrow >> 11, t = mrow & 2047;
                        int bh = b * HH + h;
                        float val = acc[mt][nt][r] + bv;
                        if (which == 0) {
                            qws[((size_t)bh * TT + t) * DH + d] = f2bf(val * 0.18033688f);
                        } else {
                            kws[((size_t)bh * TT + t) * DH + d] = f2bf(val);
                        }
                    }
                }
            }
        }
    }
}

// ---------------- flash attention v11: zero-LDS P path (r7-r10 verified) ----------------
// ROUND-22: REVERTED to __launch_bounds__(256,3). r13 (and r6) prove (256,4)
// spills: the unified VGPR+AGPR budget (arch ~84 + MFMA accumulators) exceeds
// the 128-combined cap at 4 waves/SIMD -> compiler splits 64/64 and spills
// (WRITE_SIZE 16MB -> 420MB, attn ~190us). Lesson: judge launch_bounds
// feasibility on arch+acc TOTAL, not the VGPR_Count column. (256,3) = cap
// ~170 combined, fits, ~55us verified.
__global__ void __launch_bounds__(256, 3)
attn_kernel(const u16* __restrict__ qws, const u16* __restrict__ kws,
            const u16* __restrict__ vtws, u16* __restrict__ yws) {
    __shared__ u16 Ks[2][64 * 68];
    __shared__ u16 Vs[2][64 * 68];

    const int tid  = threadIdx.x;
    const int w    = tid >> 6;
    const int lane = tid & 63;
    const int l15  = lane & 15;
    const int quad = lane >> 4;
    const int bh   = blockIdx.x;
    const int qt   = 15 - blockIdx.y;

    const u16* Kbase = kws + (size_t)bh * TT * DH;
    const u16* Vbase = vtws + (size_t)bh * DH * TT;

    const int srow  = tid >> 2;
    const int sc16  = (tid & 3) << 4;

    bf16x8 aones;
#pragma unroll
    for (int i = 0; i < 8; ++i) aones[i] = __builtin_bit_cast(bf16_t, (u16)0x3F80);

    const int q0     = qt * 128;
    const int qr0    = q0 + w * 32;
    const int ntiles = (q0 + 128) >> 6;

    const u16* Qp = qws + ((size_t)bh * TT + qr0) * DH;
    bf16x8 bqa[2], bqb[2];
#pragma unroll
    for (int kk = 0; kk < 2; ++kk) {
        bqa[kk] = *(const bf16x8*)&Qp[l15 * DH + kk * 32 + quad * 8];
        bqb[kk] = *(const bf16x8*)&Qp[(16 + l15) * DH + kk * 32 + quad * 8];
    }

    f32x4 o[2][4], ol[2];
#pragma unroll
    for (int qg = 0; qg < 2; ++qg) {
#pragma unroll
        for (int dt = 0; dt < 4; ++dt) o[qg][dt] = (f32x4){0.f, 0.f, 0.f, 0.f};
        ol[qg] = (f32x4){0.f, 0.f, 0.f, 0.f};
    }

    uint4 pk0 = *(const uint4*)&Kbase[(size_t)srow * DH + sc16];
    uint4 pk1 = *(const uint4*)&Kbase[(size_t)srow * DH + sc16 + 8];
    uint4 pv0 = *(const uint4*)&Vbase[(size_t)srow * TT + sc16];
    uint4 pv1 = *(const uint4*)&Vbase[(size_t)srow * TT + sc16 + 8];
    *(uint4*)&Ks[0][srow * 68 + sc16]     = pk0;
    *(uint4*)&Ks[0][srow * 68 + sc16 + 8] = pk1;
    *(uint4*)&Vs[0][srow * 68 + sc16]     = pv0;
    *(uint4*)&Vs[0][srow * 68 + sc16 + 8] = pv1;
    if (ntiles > 1) {
        pk0 = *(const uint4*)&Kbase[(size_t)(64 + srow) * DH + sc16];
        pk1 = *(const uint4*)&Kbase[(size_t)(64 + srow) * DH + sc16 + 8];
        pv0 = *(const uint4*)&Vbase[(size_t)srow * TT + 64 + sc16];
        pv1 = *(const uint4*)&Vbase[(size_t)srow * TT + 64 + sc16 + 8];
    }

    for (int it = 0; it < ntiles; ++it) {
        const int buf = it & 1;
        __syncthreads();

        if (it + 1 < ntiles) {
            *(uint4*)&Ks[buf ^ 1][srow * 68 + sc16]     = pk0;
            *(uint4*)&Ks[buf ^ 1][srow * 68 + sc16 + 8] = pk1;
            *(uint4*)&Vs[buf ^ 1][srow * 68 + sc16]     = pv0;
            *(uint4*)&Vs[buf ^ 1][srow * 68 + sc16 + 8] = pv1;
            if (it + 2 < ntiles) {
                int jn = (it + 2) << 6;
                pk0 = *(const uint4*)&Kbase[(size_t)(jn + srow) * DH + sc16];
                pk1 = *(const uint4*)&Kbase[(size_t)(jn + srow) * DH + sc16 + 8];
                pv0 = *(const uint4*)&Vbase[(size_t)srow * TT + jn + sc16];
                pv1 = *(const uint4*)&Vbase[(size_t)srow * TT + jn + sc16 + 8];
            }
        }

        const int j0 = it << 6;
        if (j0 > qr0 + 31) continue;

        bf16x8 ak[8];
#pragma unroll
        for (int kk = 0; kk < 2; ++kk)
#pragma unroll
            for (int kt = 0; kt < 4; ++kt)
                ak[kk * 4 + kt] =
                    *(const bf16x8*)&Ks[buf][(kt * 16 + l15) * 68 + kk * 32 + quad * 8];

        bf16x8 avr[8];
#pragma unroll
        for (int kk = 0; kk < 2; ++kk)
#pragma unroll
            for (int dt = 0; dt < 4; ++dt)
                avr[kk * 4 + dt] =
                    *(const bf16x8*)&Vs[buf][(dt * 16 + l15) * 68 + kk * 32 + quad * 8];

        f32x4 sa[4], sb[4];
#pragma unroll
        for (int kt = 0; kt < 4; ++kt) {
            sa[kt] = (f32x4){0.f, 0.f, 0.f, 0.f};
            sb[kt] = (f32x4){0.f, 0.f, 0.f, 0.f};
        }
#pragma unroll
        for (int kk = 0; kk < 2; ++kk)
#pragma unroll
            for (int kt = 0; kt < 4; ++kt)
                sa[kt] = __builtin_amdgcn_mfma_f32_16x16x32_bf16(ak[kk * 4 + kt], bqa[kk], sa[kt], 0, 0, 0);
#pragma unroll
        for (int kk = 0; kk < 2; ++kk)
#pragma unroll
            for (int kt = 0; kt < 4; ++kt)
                sb[kt] = __builtin_amdgcn_mfma_f32_16x16x32_bf16(ak[kk * 4 + kt], bqb[kk], sb[kt], 0, 0, 0);

        if (j0 + 63 > qr0) {
            int qy0 = qr0 + l15;
            int qy1 = qr0 + 16 + l15;
#pragma unroll
            for (int kt = 0; kt < 4; ++kt)
#pragma unroll
                for (int r = 0; r < 4; ++r) {
                    int key = j0 + kt * 16 + quad * 4 + r;
                    if (key > qy0) sa[kt][r] = -INFINITY;
                    if (key > qy1) sb[kt][r] = -INFINITY;
                }
        }

#pragma unroll
        for (int kt = 0; kt < 4; ++kt)
#pragma unroll
            for (int r = 0; r < 4; ++r) {
                sa[kt][r] = __builtin_amdgcn_exp2f(sa[kt][r]);
                sb[kt][r] = __builtin_amdgcn_exp2f(sb[kt][r]);
            }

        uint4 ua0, ua1, ub0, ub1;
        ua0.x = cvt_pk_bf16(sa[0][0], sa[0][1]);
        ua0.y = cvt_pk_bf16(sa[0][2], sa[0][3]);
        ua0.z = cvt_pk_bf16(sa[1][0], sa[1][1]);
        ua0.w = cvt_pk_bf16(sa[1][2], sa[1][3]);
        ua1.x = cvt_pk_bf16(sa[2][0], sa[2][1]);
        ua1.y = cvt_pk_bf16(sa[2][2], sa[2][3]);
        ua1.z = cvt_pk_bf16(sa[3][0], sa[3][1]);
        ua1.w = cvt_pk_bf16(sa[3][2], sa[3][3]);
        ub0.x = cvt_pk_bf16(sb[0][0], sb[0][1]);
        ub0.y = cvt_pk_bf16(sb[0][2], sb[0][3]);
        ub0.z = cvt_pk_bf16(sb[1][0], sb[1][1]);
        ub0.w = cvt_pk_bf16(sb[1][2], sb[1][3]);
        ub1.x = cvt_pk_bf16(sb[2][0], sb[2][1]);
        ub1.y = cvt_pk_bf16(sb[2][2], sb[2][3]);
        ub1.z = cvt_pk_bf16(sb[3][0], sb[3][1]);
        ub1.w = cvt_pk_bf16(sb[3][2], sb[3][3]);
        bf16x8 bpa0 = __builtin_bit_cast(bf16x8, ua0);
        bf16x8 bpa1 = __builtin_bit_cast(bf16x8, ua1);
        bf16x8 bpb0 = __builtin_bit_cast(bf16x8, ub0);
        bf16x8 bpb1 = __builtin_bit_cast(bf16x8, ub1);

#pragma unroll
        for (int dt = 0; dt < 4; ++dt)
            o[0][dt] = __builtin_amdgcn_mfma_f32_16x16x32_bf16(avr[dt], bpa0, o[0][dt], 0, 0, 0);
        ol[0] = __builtin_amdgcn_mfma_f32_16x16x32_bf16(aones, bpa0, ol[0], 0, 0, 0);
#pragma unroll
        for (int dt = 0; dt < 4; ++dt)
            o[0][dt] = __builtin_amdgcn_mfma_f32_16x16x32_bf16(avr[4 + dt], bpa1, o[0][dt], 0, 0, 0);
        ol[0] = __builtin_amdgcn_mfma_f32_16x16x32_bf16(aones, bpa1, ol[0], 0, 0, 0);
#pragma unroll
        for (int dt = 0; dt < 4; ++dt)
            o[1][dt] = __builtin_amdgcn_mfma_f32_16x16x32_bf16(avr[dt], bpb0, o[1][dt], 0, 0, 0);
        ol[1] = __builtin_amdgcn_mfma_f32_16x16x32_bf16(aones, bpb0, ol[1], 0, 0, 0);
#pragma unroll
        for (int dt = 0; dt < 4; ++dt)
            o[1][dt] = __builtin_amdgcn_mfma_f32_16x16x32_bf16(avr[4 + dt], bpb1, o[1][dt], 0, 0, 0);
        ol[1] = __builtin_amdgcn_mfma_f32_16x16x32_bf16(aones, bpb1, ol[1], 0, 0, 0);
    }

#pragma unroll
    for (int qg = 0; qg < 2; ++qg) {
        float rinv = __builtin_amdgcn_rcpf(ol[qg][0]);
        int t = qr0 + qg * 16 + l15;
#pragma unroll
        for (int dt = 0; dt < 4; ++dt) {
            uint2 yv;
            yv.x = cvt_pk_bf16(o[qg][dt][0] * rinv, o[qg][dt][1] * rinv);
            yv.y = cvt_pk_bf16(o[qg][dt][2] * rinv, o[qg][dt][3] * rinv);
            *(uint2*)&yws[((size_t)bh * TT + t) * DH + dt * 16 + quad * 4] = yv;
        }
    }
}

// ---------------- launch ----------------

extern "C" void kernel_launch(void* const* d_in, const int* in_sizes, int n_in,
                              void* d_out, int out_size, void* d_ws, size_t ws_size,
                              hipStream_t stream) {
    const float* x     = (const float*)d_in[0];
    const float* W_qkv = (const float*)d_in[1];
    const float* b_qkv = (const float*)d_in[2];
    const float* W_out = (const float*)d_in[3];
    const float* b_out = (const float*)d_in[4];
    float* out = (float*)d_out;

    char* ws = (char*)d_ws;
    u16* xb   = (u16*)ws; ws += (size_t)MM * CC * 2;       // x bf16        16 MB
    u16* wqt  = (u16*)ws; ws += (size_t)3 * CC * CC * 2;   // W_qkv^T bf16   6 MB
    u16* wot  = (u16*)ws; ws += (size_t)CC * CC * 2;       // W_out^T bf16   2 MB
    u16* qws  = (u16*)ws; ws += (size_t)MM * CC * 2;       // Q [B,H,T,Dh]  16 MB
    u16* kws  = (u16*)ws; ws += (size_t)MM * CC * 2;       // K [B,H,T,Dh]  16 MB
    u16* vtws = (u16*)ws; ws += (size_t)MM * CC * 2;       // V^T (key-permuted) 16 MB
    u16* yws  = (u16*)ws; ws += (size_t)MM * CC * 2;       // y [B,H,T,Dh]  16 MB

    prep_kernel<<<8192 + 3072 + 1024, 256, 0, stream>>>(x, xb, W_qkv, wqt, W_out, wot);

    gemm_bt_kernel<1><<<dim3(24, 64), 256, 0, stream>>>(
        xb, wqt, b_qkv, nullptr, qws, kws, vtws, MM, 3 * CC, CC);

    attn_kernel<<<dim3(BB * HH, 16), 256, 0, stream>>>(qws, kws, vtws, yws);

    gemm_bt_kernel<0><<<dim3(8, 64), 256, 0, stream>>>(
        yws, wot, b_out, out, nullptr, nullptr, nullptr, MM, CC, CC);
}

// Round 15
// 232.334 us; speedup vs baseline: 1.5732x; 1.0089x over previous
//
#include <hip/hip_runtime.h>
#include <cstdint>
#include <math.h>

#define TT 2048
#define CC 1024
#define HH 16
#define DH 64
#define BB 4
#define MM 8192   // B*T

typedef unsigned short u16;
typedef __bf16 bf16_t;
typedef bf16_t bf16x8 __attribute__((ext_vector_type(8)));
typedef float f32x4 __attribute__((ext_vector_type(4)));

// fp32 -> bf16 round-to-nearest-even (scalar)
static __device__ inline u16 f2bf(float f) {
    unsigned int u = __builtin_bit_cast(unsigned int, f);
    unsigned int lsb = (u >> 16) & 1u;
    u += 0x7fffu + lsb;
    return (u16)(u >> 16);
}

// packed 2xfp32 -> 2xbf16 (gfx950 v_cvt_pk_bf16_f32, RNE)
static __device__ inline unsigned int cvt_pk_bf16(float a, float b) {
    unsigned int r;
    asm volatile("v_cvt_pk_bf16_f32 %0, %1, %2" : "=v"(r) : "v"(a), "v"(b));
    return r;
}

// async 16B global->LDS (LDS dest wave-uniform + lane*16B)
#define GLL16(gptr, lptr)                                                            \
    __builtin_amdgcn_global_load_lds(                                                \
        (__attribute__((address_space(1))) void*)(gptr),                             \
        (__attribute__((address_space(3))) void*)(lptr), 16, 0, 0)

// ---------------- fused prep kernel (r18-verified) ----------------
__global__ void __launch_bounds__(256)
prep_kernel(const float* __restrict__ x, u16* __restrict__ xb,
            const float* __restrict__ Wq, u16* __restrict__ wqt,
            const float* __restrict__ Wo, u16* __restrict__ wot) {
    const int bid = blockIdx.x;
    if (bid < 8192) {                       // cast x
        int i = bid * 256 + threadIdx.x;
        float4 v = ((const float4*)x)[i];
        uint2 o;
        o.x = cvt_pk_bf16(v.x, v.y);
        o.y = cvt_pk_bf16(v.z, v.w);
        ((uint2*)xb)[i] = o;
        return;
    }
    __shared__ u16 tile[32 * 34];
    const float* W; u16* Wt; int N, n0, k0;
    if (bid < 8192 + 3072) {                // W_qkv
        int idx = bid - 8192;
        W = Wq; Wt = wqt; N = 3 * CC;
        n0 = (idx % 96) * 32; k0 = (idx / 96) * 32;
    } else {                                // W_out
        int idx = bid - 11264;
        W = Wo; Wt = wot; N = CC;
        n0 = (idx % 32) * 32; k0 = (idx / 32) * 32;
    }
    const int tx = threadIdx.x & 31;
    const int ty = threadIdx.x >> 5;
#pragma unroll
    for (int i = 0; i < 4; ++i) {
        int k = ty + i * 8;
        tile[tx * 34 + k] = f2bf(W[(size_t)(k0 + k) * N + n0 + tx]);
    }
    __syncthreads();
    const int tx2 = threadIdx.x & 15;
    const int ty2 = threadIdx.x >> 4;
#pragma unroll
    for (int i = 0; i < 2; ++i) {
        int r = ty2 + i * 16;
        *(unsigned int*)&Wt[(size_t)(n0 + r) * CC + k0 + 2 * tx2] =
            *(unsigned int*)&tile[r * 34 + 2 * tx2];
    }
}

// ---------------- GEMM1: faithful 8-phase 256x256 (ROUND-23) ----------------
// r14 confirmed: FETCH -20% (XCD swizzle) but dur flat -> 2-phase ceiling is
// compute-structural. This is the faithful template port (r11's failure modes
// fixed per m196's ablation): TWO barriers per phase (lockstep role-split),
// 8 ds_read_b128 + 1 half-tile stage + 16 MFMA per phase, counted vmcnt at
// K-half boundaries only, setprio around MFMA (T5 pays in 8-phase, m218b),
// XCD-chunked swizzle (verified r14).
// vmcnt LEDGER (2 GLL16/stage/thread, deadline order Ak0,Bk0,Ak1,Bk1):
//   phase 0 entry: outstanding = 4 half-tiles of tile t (8 loads) ->
//     vmcnt(4) drains oldest 4 = {Ak0,Bk0}(t). barrier publishes.
//   phase 2 entry: outstanding = {Ak1,Bk1}(t) + {Ak0,Bk0}(t+1) = 8 ->
//     vmcnt(4) drains {Ak1,Bk1}(t); last tile (nothing staged): vmcnt(0).
//   Stage at tile t writes buf^1; its last readers finished before tile t's
//   first barrier -> write-safe. All waves execute identical barrier counts.
__global__ void __launch_bounds__(512, 1)
gemm1_kernel(const u16* __restrict__ A, const u16* __restrict__ Bt,
             const float* __restrict__ bias,
             u16* __restrict__ qws, u16* __restrict__ kws, u16* __restrict__ vtws) {
    __shared__ u16 lds[65536];   // 128 KB: A[buf][kh] @ (buf*2+kh)*8192, B @ +32768

    const int tid  = threadIdx.x;          // 0..511
    const int w    = tid >> 6;             // 0..7
    const int lane = tid & 63;
    const int l15  = lane & 15;
    const int quad = lane >> 4;
    const int wm2  = w >> 2;               // 0..1: row half (128)
    const int wn4  = w & 3;                // 0..3: col quarter (64)

    // XCD-chunked swizzle (grid 12x32 = 384, %8==0 -> bijective)
    const int nwg  = gridDim.x * gridDim.y;
    const int bidl = blockIdx.y * gridDim.x + blockIdx.x;
    const int swz  = (bidl & 7) * (nwg >> 3) + (bidl >> 3);
    const int m0   = (swz / gridDim.x) * 256;
    const int n0   = (swz % gridDim.x) * 256;

    const int csw  = (quad ^ ((l15 >> 1) & 3)) * 8;  // swizzled read col (u16)

    // staging: row = j*128 + (tid>>2); phys col-group = tid&3 (XOR-swizzled src)
    const int srow = tid >> 2;             // 0..127 (+ j*128)
    const int sgl  = ((tid & 3) ^ ((srow >> 1) & 3)) * 8;  // logical col fetched

    f32x4 acc[8][4];
#pragma unroll
    for (int i = 0; i < 8; ++i)
#pragma unroll
        for (int j = 0; j < 4; ++j) acc[i][j] = (f32x4){0.f, 0.f, 0.f, 0.f};

    auto stA = [&](int buf, int kh, int kt) {
#pragma unroll
        for (int j = 0; j < 2; ++j) {
            int row = j * 128 + srow;
            GLL16(&A[(size_t)(m0 + row) * CC + kt * 64 + kh * 32 + sgl],
                  &lds[(size_t)(buf * 2 + kh) * 8192 + (j * 512 + tid) * 8]);
        }
    };
    auto stB = [&](int buf, int kh, int kt) {
#pragma unroll
        for (int j = 0; j < 2; ++j) {
            int row = j * 128 + srow;
            GLL16(&Bt[(size_t)(n0 + row) * CC + kt * 64 + kh * 32 + sgl],
                  &lds[32768 + (size_t)(buf * 2 + kh) * 8192 + (j * 512 + tid) * 8]);
        }
    };

    const int ntiles = CC / 64;            // 16
    // prologue: tile 0 in deadline order
    stA(0, 0, 0); stB(0, 0, 0); stA(0, 1, 0); stB(0, 1, 0);

    for (int t = 0; t < ntiles; ++t) {
        const int buf  = t & 1;
        const int nbuf = buf ^ 1;
        const bool more = (t + 1 < ntiles);

#pragma unroll
        for (int q = 0; q < 4; ++q) {
            const int kk = q >> 1;
            const int mq = q & 1;

            if (q == 0) {
                asm volatile("s_waitcnt vmcnt(4)" ::: "memory");
                __builtin_amdgcn_s_barrier();
                __builtin_amdgcn_sched_barrier(0);
            } else if (q == 2) {
                if (more) asm volatile("s_waitcnt vmcnt(4)" ::: "memory");
                else      asm volatile("s_waitcnt vmcnt(0)" ::: "memory");
                __builtin_amdgcn_s_barrier();
                __builtin_amdgcn_sched_barrier(0);
            }

            // ds-read this phase's operand subtile (8 x ds_read_b128)
            bf16x8 af[4], bfm[4];
            const int abase = (buf * 2 + kk) * 8192;
            const int bbase = 32768 + (buf * 2 + kk) * 8192;
#pragma unroll
            for (int i = 0; i < 4; ++i)
                af[i] = *(const bf16x8*)&lds[abase + (wm2 * 128 + (mq * 4 + i) * 16 + l15) * 32 + csw];
#pragma unroll
            for (int nt = 0; nt < 4; ++nt)
                bfm[nt] = *(const bf16x8*)&lds[bbase + (wn4 * 64 + nt * 16 + l15) * 32 + csw];

            // stage ONE half-tile of tile t+1 (deadline order)
            if (more) {
                if      (q == 0) stA(nbuf, 0, t + 1);
                else if (q == 1) stB(nbuf, 0, t + 1);
                else if (q == 2) stA(nbuf, 1, t + 1);
                else             stB(nbuf, 1, t + 1);
            }

            asm volatile("s_waitcnt lgkmcnt(0)" ::: "memory");
            __builtin_amdgcn_sched_barrier(0);
            __builtin_amdgcn_s_setprio(1);
#pragma unroll
            for (int i = 0; i < 4; ++i)
#pragma unroll
                for (int nt = 0; nt < 4; ++nt)
                    acc[mq * 4 + i][nt] = __builtin_amdgcn_mfma_f32_16x16x32_bf16(
                        af[i], bfm[nt], acc[mq * 4 + i][nt], 0, 0, 0);
            __builtin_amdgcn_s_setprio(0);
            __builtin_amdgcn_s_barrier();
        }
    }

    // epilogue: qkv scatter (Q scale-folded, K, V^T key-permuted) — r11-verified
#pragma unroll
    for (int mt = 0; mt < 8; ++mt) {
        int mrow_base = m0 + wm2 * 128 + mt * 16 + quad * 4;
#pragma unroll
        for (int nt = 0; nt < 4; ++nt) {
            int ncol = n0 + wn4 * 64 + nt * 16 + l15;
            float bv = bias[ncol];
            int which = ncol >> 10, c = ncol & 1023;
            int h = c >> 6, d = c & 63;
            if (which == 2) {
                int b = mrow_base >> 11, t = mrow_base & 2047;
                int bh = b * HH + h;
                int ch = (t >> 2) & 15;
                int chp = (ch & 8) | (((ch >> 1) & 1) << 2) | ((ch & 1) << 1) | ((ch >> 2) & 1);
                int tp = (t & ~63) | (chp << 2);
                uint2 pv;
                pv.x = cvt_pk_bf16(acc[mt][nt][0] + bv, acc[mt][nt][1] + bv);
                pv.y = cvt_pk_bf16(acc[mt][nt][2] + bv, acc[mt][nt][3] + bv);
                *(uint2*)&vtws[((size_t)bh * DH + d) * TT + tp] = pv;
            } else {
#pragma unroll
                for (int r = 0; r < 4; ++r) {
                    int mrow = mrow_base + r;
                    int b = mrow >> 11, t = mrow & 2047;
                    int bh = b * HH + h;
                    float val = acc[mt][nt][r] + bv;
                    if (which == 0) {
                        qws[((size_t)bh * TT + t) * DH + d] = f2bf(val * 0.18033688f);
                    } else {
                        kws[((size_t)bh * TT + t) * DH + d] = f2bf(val);
                    }
                }
            }
        }
    }
}

// ---------------- GEMM (2-phase 128x128 + XCD swizzle, r14-verified) — gemm2 ----------------
template <int MODE>
__global__ void __launch_bounds__(256)
gemm_bt_kernel(const u16* __restrict__ A, const u16* __restrict__ Bt,
               const float* __restrict__ bias, float* __restrict__ Cout,
               u16* __restrict__ qws, u16* __restrict__ kws, u16* __restrict__ vtws,
               int Mdim, int Ndim, int Kdim) {
    __shared__ u16 As[2][128 * 32];
    __shared__ u16 Bs[2][128 * 32];

    const int tid  = threadIdx.x;
    const int w    = tid >> 6;
    const int lane = tid & 63;
    const int l15  = lane & 15;
    const int quad = lane >> 4;
    const int wm   = (w & 1) * 64;
    const int wn   = (w >> 1) * 64;

    const int nwg = gridDim.x * gridDim.y;
    const int bid = blockIdx.y * gridDim.x + blockIdx.x;
    const int swz = (bid & 7) * (nwg >> 3) + (bid >> 3);
    const int m0  = (swz / gridDim.x) * 128;
    const int n0  = (swz % gridDim.x) * 128;

    const int row0  = tid >> 2;
    const int row1  = row0 + 64;
    const int colsw = (((tid & 3) ^ ((row0 >> 1) & 3))) << 3;

    f32x4 acc[4][4];
#pragma unroll
    for (int i = 0; i < 4; ++i)
#pragma unroll
        for (int j = 0; j < 4; ++j) acc[i][j] = (f32x4){0.f, 0.f, 0.f, 0.f};

    auto stageA = [&](int buf, int kc) {
        if (MODE == 0) {
            int kcc = kc + colsw, h = kcc >> 6, d = kcc & 63;
            int m = m0 + row0, b = m >> 11, t = m & 2047;
            GLL16(&A[(((size_t)(b * HH + h) * TT + t) * DH) + d], &As[buf][tid * 8]);
            m = m0 + row1; b = m >> 11; t = m & 2047;
            GLL16(&A[(((size_t)(b * HH + h) * TT + t) * DH) + d], &As[buf][(tid + 256) * 8]);
        } else {
            GLL16(&A[(size_t)(m0 + row0) * Kdim + kc + colsw], &As[buf][tid * 8]);
            GLL16(&A[(size_t)(m0 + row1) * Kdim + kc + colsw], &As[buf][(tid + 256) * 8]);
        }
    };

    stageA(0, 0);
    GLL16(&Bt[(size_t)(n0 + row0) * Kdim + colsw], &Bs[0][tid * 8]);
    GLL16(&Bt[(size_t)(n0 + row1) * Kdim + colsw], &Bs[0][(tid + 256) * 8]);

    const int csw = (quad ^ ((l15 >> 1) & 3)) * 8;

    const int nsteps = Kdim >> 5;
    for (int it = 0; it < nsteps; ++it) {
        const int buf = it & 1;
        __syncthreads();

        if (it + 1 < nsteps) {
            const int nbuf = buf ^ 1;
            const int kc = (it + 1) << 5;
            stageA(nbuf, kc);
            GLL16(&Bt[(size_t)(n0 + row0) * Kdim + kc + colsw], &Bs[nbuf][tid * 8]);
            GLL16(&Bt[(size_t)(n0 + row1) * Kdim + kc + colsw], &Bs[nbuf][(tid + 256) * 8]);
        }

        bf16x8 af[4], bfm[4];
#pragma unroll
        for (int mt = 0; mt < 4; ++mt)
            af[mt] = *(const bf16x8*)&As[buf][(wm + mt * 16 + l15) * 32 + csw];
#pragma unroll
        for (int nt = 0; nt < 4; ++nt)
            bfm[nt] = *(const bf16x8*)&Bs[buf][(wn + nt * 16 + l15) * 32 + csw];
#pragma unroll
        for (int mt = 0; mt < 4; ++mt)
#pragma unroll
            for (int nt = 0; nt < 4; ++nt)
                acc[mt][nt] = __builtin_amdgcn_mfma_f32_16x16x32_bf16(
                    af[mt], bfm[nt], acc[mt][nt], 0, 0, 0);
    }

#pragma unroll
    for (int mt = 0; mt < 4; ++mt) {
        int mrow_base = m0 + wm + mt * 16 + quad * 4;
#pragma unroll
        for (int nt = 0; nt < 4; ++nt) {
            int ncol = n0 + wn + nt * 16 + l15;
            float bv = bias[ncol];
            if (MODE == 0) {
#pragma unroll
                for (int r = 0; r < 4; ++r)
                    Cout[(size_t)(mrow_base + r) * Ndim + ncol] = acc[mt][nt][r] + bv;
            } else {
                int which = ncol >> 10, c = ncol & 1023;
                int h = c >> 6, d = c & 63;
                if (which == 2) {
                    int b = mrow_base >> 11, t = mrow_base & 2047;
                    int bh = b * HH + h;
                    int ch = (t >> 2) & 15;
                    int chp = (ch & 8) | (((ch >> 1) & 1) << 2) | ((ch & 1) << 1) | ((ch >> 2) & 1);
                    int tp = (t & ~63) | (chp << 2);
                    uint2 pv;
                    pv.x = cvt_pk_bf16(acc[mt][nt][0] + bv, acc[mt][nt][1] + bv);
                    pv.y = cvt_pk_bf16(acc[mt][nt][2] + bv, acc[mt][nt][3] + bv);
                    *(uint2*)&vtws[((size_t)bh * DH + d) * TT + tp] = pv;
                } else {
#pragma unroll
                    for (int r = 0; r < 4; ++r) {
                        int mrow = mrow_base + r;
                        int b = mrow >> 11, t = mrow & 2047;
                        int bh = b * HH + h;
                        float val = acc[mt][nt][r] + bv;
                        if (which == 0) {
                            qws[((size_t)bh * TT + t) * DH + d] = f2bf(val * 0.18033688f);
                        } else {
                            kws[((size_t)bh * TT + t) * DH + d] = f2bf(val);
                        }
                    }
                }
            }
        }
    }
}

// ---------------- flash attention v11: zero-LDS P path (r7-r10/r14 verified) ----------------
__global__ void __launch_bounds__(256, 3)
attn_kernel(const u16* __restrict__ qws, const u16* __restrict__ kws,
            const u16* __restrict__ vtws, u16* __restrict__ yws) {
    __shared__ u16 Ks[2][64 * 68];
    __shared__ u16 Vs[2][64 * 68];

    const int tid  = threadIdx.x;
    const int w    = tid >> 6;
    const int lane = tid & 63;
    const int l15  = lane & 15;
    const int quad = lane >> 4;
    const int bh   = blockIdx.x;
    const int qt   = 15 - blockIdx.y;

    const u16* Kbase = kws + (size_t)bh * TT * DH;
    const u16* Vbase = vtws + (size_t)bh * DH * TT;

    const int srow  = tid >> 2;
    const int sc16  = (tid & 3) << 4;

    bf16x8 aones;
#pragma unroll
    for (int i = 0; i < 8; ++i) aones[i] = __builtin_bit_cast(bf16_t, (u16)0x3F80);

    const int q0     = qt * 128;
    const int qr0    = q0 + w * 32;
    const int ntiles = (q0 + 128) >> 6;

    const u16* Qp = qws + ((size_t)bh * TT + qr0) * DH;
    bf16x8 bqa[2], bqb[2];
#pragma unroll
    for (int kk = 0; kk < 2; ++kk) {
        bqa[kk] = *(const bf16x8*)&Qp[l15 * DH + kk * 32 + quad * 8];
        bqb[kk] = *(const bf16x8*)&Qp[(16 + l15) * DH + kk * 32 + quad * 8];
    }

    f32x4 o[2][4], ol[2];
#pragma unroll
    for (int qg = 0; qg < 2; ++qg) {
#pragma unroll
        for (int dt = 0; dt < 4; ++dt) o[qg][dt] = (f32x4){0.f, 0.f, 0.f, 0.f};
        ol[qg] = (f32x4){0.f, 0.f, 0.f, 0.f};
    }

    uint4 pk0 = *(const uint4*)&Kbase[(size_t)srow * DH + sc16];
    uint4 pk1 = *(const uint4*)&Kbase[(size_t)srow * DH + sc16 + 8];
    uint4 pv0 = *(const uint4*)&Vbase[(size_t)srow * TT + sc16];
    uint4 pv1 = *(const uint4*)&Vbase[(size_t)srow * TT + sc16 + 8];
    *(uint4*)&Ks[0][srow * 68 + sc16]     = pk0;
    *(uint4*)&Ks[0][srow * 68 + sc16 + 8] = pk1;
    *(uint4*)&Vs[0][srow * 68 + sc16]     = pv0;
    *(uint4*)&Vs[0][srow * 68 + sc16 + 8] = pv1;
    if (ntiles > 1) {
        pk0 = *(const uint4*)&Kbase[(size_t)(64 + srow) * DH + sc16];
        pk1 = *(const uint4*)&Kbase[(size_t)(64 + srow) * DH + sc16 + 8];
        pv0 = *(const uint4*)&Vbase[(size_t)srow * TT + 64 + sc16];
        pv1 = *(const uint4*)&Vbase[(size_t)srow * TT + 64 + sc16 + 8];
    }

    for (int it = 0; it < ntiles; ++it) {
        const int buf = it & 1;
        __syncthreads();

        if (it + 1 < ntiles) {
            *(uint4*)&Ks[buf ^ 1][srow * 68 + sc16]     = pk0;
            *(uint4*)&Ks[buf ^ 1][srow * 68 + sc16 + 8] = pk1;
            *(uint4*)&Vs[buf ^ 1][srow * 68 + sc16]     = pv0;
            *(uint4*)&Vs[buf ^ 1][srow * 68 + sc16 + 8] = pv1;
            if (it + 2 < ntiles) {
                int jn = (it + 2) << 6;
                pk0 = *(const uint4*)&Kbase[(size_t)(jn + srow) * DH + sc16];
                pk1 = *(const uint4*)&Kbase[(size_t)(jn + srow) * DH + sc16 + 8];
                pv0 = *(const uint4*)&Vbase[(size_t)srow * TT + jn + sc16];
                pv1 = *(const uint4*)&Vbase[(size_t)srow * TT + jn + sc16 + 8];
            }
        }

        const int j0 = it << 6;
        if (j0 > qr0 + 31) continue;

        bf16x8 ak[8];
#pragma unroll
        for (int kk = 0; kk < 2; ++kk)
#pragma unroll
            for (int kt = 0; kt < 4; ++kt)
                ak[kk * 4 + kt] =
                    *(const bf16x8*)&Ks[buf][(kt * 16 + l15) * 68 + kk * 32 + quad * 8];

        bf16x8 avr[8];
#pragma unroll
        for (int kk = 0; kk < 2; ++kk)
#pragma unroll
            for (int dt = 0; dt < 4; ++dt)
                avr[kk * 4 + dt] =
                    *(const bf16x8*)&Vs[buf][(dt * 16 + l15) * 68 + kk * 32 + quad * 8];

        f32x4 sa[4], sb[4];
#pragma unroll
        for (int kt = 0; kt < 4; ++kt) {
            sa[kt] = (f32x4){0.f, 0.f, 0.f, 0.f};
            sb[kt] = (f32x4){0.f, 0.f, 0.f, 0.f};
        }
#pragma unroll
        for (int kk = 0; kk < 2; ++kk)
#pragma unroll
            for (int kt = 0; kt < 4; ++kt)
                sa[kt] = __builtin_amdgcn_mfma_f32_16x16x32_bf16(ak[kk * 4 + kt], bqa[kk], sa[kt], 0, 0, 0);
#pragma unroll
        for (int kk = 0; kk < 2; ++kk)
#pragma unroll
            for (int kt = 0; kt < 4; ++kt)
                sb[kt] = __builtin_amdgcn_mfma_f32_16x16x32_bf16(ak[kk * 4 + kt], bqb[kk], sb[kt], 0, 0, 0);

        if (j0 + 63 > qr0) {
            int qy0 = qr0 + l15;
            int qy1 = qr0 + 16 + l15;
#pragma unroll
            for (int kt = 0; kt < 4; ++kt)
#pragma unroll
                for (int r = 0; r < 4; ++r) {
                    int key = j0 + kt * 16 + quad * 4 + r;
                    if (key > qy0) sa[kt][r] = -INFINITY;
                    if (key > qy1) sb[kt][r] = -INFINITY;
                }
        }

#pragma unroll
        for (int kt = 0; kt < 4; ++kt)
#pragma unroll
            for (int r = 0; r < 4; ++r) {
                sa[kt][r] = __builtin_amdgcn_exp2f(sa[kt][r]);
                sb[kt][r] = __builtin_amdgcn_exp2f(sb[kt][r]);
            }

        uint4 ua0, ua1, ub0, ub1;
        ua0.x = cvt_pk_bf16(sa[0][0], sa[0][1]);
        ua0.y = cvt_pk_bf16(sa[0][2], sa[0][3]);
        ua0.z = cvt_pk_bf16(sa[1][0], sa[1][1]);
        ua0.w = cvt_pk_bf16(sa[1][2], sa[1][3]);
        ua1.x = cvt_pk_bf16(sa[2][0], sa[2][1]);
        ua1.y = cvt_pk_bf16(sa[2][2], sa[2][3]);
        ua1.z = cvt_pk_bf16(sa[3][0], sa[3][1]);
        ua1.w = cvt_pk_bf16(sa[3][2], sa[3][3]);
        ub0.x = cvt_pk_bf16(sb[0][0], sb[0][1]);
        ub0.y = cvt_pk_bf16(sb[0][2], sb[0][3]);
        ub0.z = cvt_pk_bf16(sb[1][0], sb[1][1]);
        ub0.w = cvt_pk_bf16(sb[1][2], sb[1][3]);
        ub1.x = cvt_pk_bf16(sb[2][0], sb[2][1]);
        ub1.y = cvt_pk_bf16(sb[2][2], sb[2][3]);
        ub1.z = cvt_pk_bf16(sb[3][0], sb[3][1]);
        ub1.w = cvt_pk_bf16(sb[3][2], sb[3][3]);
        bf16x8 bpa0 = __builtin_bit_cast(bf16x8, ua0);
        bf16x8 bpa1 = __builtin_bit_cast(bf16x8, ua1);
        bf16x8 bpb0 = __builtin_bit_cast(bf16x8, ub0);
        bf16x8 bpb1 = __builtin_bit_cast(bf16x8, ub1);

#pragma unroll
        for (int dt = 0; dt < 4; ++dt)
            o[0][dt] = __builtin_amdgcn_mfma_f32_16x16x32_bf16(avr[dt], bpa0, o[0][dt], 0, 0, 0);
        ol[0] = __builtin_amdgcn_mfma_f32_16x16x32_bf16(aones, bpa0, ol[0], 0, 0, 0);
#pragma unroll
        for (int dt = 0; dt < 4; ++dt)
            o[0][dt] = __builtin_amdgcn_mfma_f32_16x16x32_bf16(avr[4 + dt], bpa1, o[0][dt], 0, 0, 0);
        ol[0] = __builtin_amdgcn_mfma_f32_16x16x32_bf16(aones, bpa1, ol[0], 0, 0, 0);
#pragma unroll
        for (int dt = 0; dt < 4; ++dt)
            o[1][dt] = __builtin_amdgcn_mfma_f32_16x16x32_bf16(avr[dt], bpb0, o[1][dt], 0, 0, 0);
        ol[1] = __builtin_amdgcn_mfma_f32_16x16x32_bf16(aones, bpb0, ol[1], 0, 0, 0);
#pragma unroll
        for (int dt = 0; dt < 4; ++dt)
            o[1][dt] = __builtin_amdgcn_mfma_f32_16x16x32_bf16(avr[4 + dt], bpb1, o[1][dt], 0, 0, 0);
        ol[1] = __builtin_amdgcn_mfma_f32_16x16x32_bf16(aones, bpb1, ol[1], 0, 0, 0);
    }

#pragma unroll
    for (int qg = 0; qg < 2; ++qg) {
        float rinv = __builtin_amdgcn_rcpf(ol[qg][0]);
        int t = qr0 + qg * 16 + l15;
#pragma unroll
        for (int dt = 0; dt < 4; ++dt) {
            uint2 yv;
            yv.x = cvt_pk_bf16(o[qg][dt][0] * rinv, o[qg][dt][1] * rinv);
            yv.y = cvt_pk_bf16(o[qg][dt][2] * rinv, o[qg][dt][3] * rinv);
            *(uint2*)&yws[((size_t)bh * TT + t) * DH + dt * 16 + quad * 4] = yv;
        }
    }
}

// ---------------- launch ----------------

extern "C" void kernel_launch(void* const* d_in, const int* in_sizes, int n_in,
                              void* d_out, int out_size, void* d_ws, size_t ws_size,
                              hipStream_t stream) {
    const float* x     = (const float*)d_in[0];
    const float* W_qkv = (const float*)d_in[1];
    const float* b_qkv = (const float*)d_in[2];
    const float* W_out = (const float*)d_in[3];
    const float* b_out = (const float*)d_in[4];
    float* out = (float*)d_out;

    char* ws = (char*)d_ws;
    u16* xb   = (u16*)ws; ws += (size_t)MM * CC * 2;       // x bf16        16 MB
    u16* wqt  = (u16*)ws; ws += (size_t)3 * CC * CC * 2;   // W_qkv^T bf16   6 MB
    u16* wot  = (u16*)ws; ws += (size_t)CC * CC * 2;       // W_out^T bf16   2 MB
    u16* qws  = (u16*)ws; ws += (size_t)MM * CC * 2;       // Q [B,H,T,Dh]  16 MB
    u16* kws  = (u16*)ws; ws += (size_t)MM * CC * 2;       // K [B,H,T,Dh]  16 MB
    u16* vtws = (u16*)ws; ws += (size_t)MM * CC * 2;       // V^T (key-permuted) 16 MB
    u16* yws  = (u16*)ws; ws += (size_t)MM * CC * 2;       // y [B,H,T,Dh]  16 MB

    prep_kernel<<<8192 + 3072 + 1024, 256, 0, stream>>>(x, xb, W_qkv, wqt, W_out, wot);

    gemm1_kernel<<<dim3(12, 32), 512, 0, stream>>>(xb, wqt, b_qkv, qws, kws, vtws);

    attn_kernel<<<dim3(BB * HH, 16), 256, 0, stream>>>(qws, kws, vtws, yws);

    gemm_bt_kernel<0><<<dim3(8, 64), 256, 0, stream>>>(
        yws, wot, b_out, out, nullptr, nullptr, nullptr, MM, CC, CC);
}